// Round 8
// baseline (188.844 us; speedup 1.0000x reference)
//
#include <hip/hip_runtime.h>
#include <math.h>

#define N      4096
#define NIMG   2048
#define TXN    248           // net output cols per block (64 lanes x float4 - 8 halo)
#define BSPAN  260           // x-range for staged-row computation (cols x0-4..x0+255)
#define HRW    16            // output rows per wave (block = 64 rows, 4 waves stacked)
#define PPI    39            // img patch pitch (odd -> bank-spread; ncols <= 38)
#define PR     132           // img patch rows
#define IPSZ   (PR * PPI)    // 5148 floats
#define NSX    17            // ceil(4096/248)
#define NSY    64            // 4096/64
#define NBLK   (NSX * NSY)   // 1088 blocks

// Gaussian kernel sigma=1, r=4 (double-precision eval of reference formula)
#define KW0 0.00013383063f
#define KW1 0.00443186160f
#define KW2 0.05399112800f
#define KW3 0.24197144000f
#define KW4 0.39894346870f

__device__ __forceinline__ int symi(int g) {
    g = (g < 0) ? (-1 - g) : g;
    g = (g >= N) ? (2 * N - 1 - g) : g;
    return g;
}

#define H9(A,B,C,D,E,F,G,H,I)                                                  \
    fmaf(KW0,(A), fmaf(KW1,(B), fmaf(KW2,(C), fmaf(KW3,(D), fmaf(KW4,(E),      \
    fmaf(KW3,(F), fmaf(KW2,(G), fmaf(KW1,(H), KW0*(I)))))))))

// g-column J: bilinear-x for this lane's 4 output cols (extends verified
// R5 GCOL2: cols 2a,2a+1,2a+2,2a+3 tap patch rows p2..pm = 2048-a..2045-a)
#define GCOL4(J, G) do {                                                       \
    const float pm_ = ipg[(J) - 2 * PPI];                                      \
    const float p0_ = ipg[(J) - PPI];                                          \
    const float p1_ = ipg[(J)];                                                \
    const float p2_ = ipg[(J) + PPI];                                          \
    (G).x = fmaf(0.75f, p1_, 0.25f * p2_);                                     \
    (G).y = fmaf(0.25f, p0_, 0.75f * p1_);                                     \
    (G).z = fmaf(0.75f, p0_, 0.25f * p1_);                                     \
    (G).w = fmaf(0.25f, pm_, 0.75f * p0_);                                     \
} while (0)

#define DM4(DST, W0, GA_, W1, GB_, NZ) do {                                    \
    (DST).x = fmaf(W0, (GA_).x, fmaf(W1, (GB_).x, 0.01f * (NZ).x));            \
    (DST).y = fmaf(W0, (GA_).y, fmaf(W1, (GB_).y, 0.01f * (NZ).y));            \
    (DST).z = fmaf(W0, (GA_).z, fmaf(W1, (GB_).z, 0.01f * (NZ).z));            \
    (DST).w = fmaf(W0, (GA_).w, fmaf(W1, (GB_).w, 0.01f * (NZ).w));            \
} while (0)

// 4 D rows from carried g-cols (ga,gb) + 2 fresh (J2, J2+1); verified weight
// pattern (.25,.75)(.75,.25)(.25,.75)(.75,.25)  [R3/R5/R6]
#define PROD4(J2, D0, D1, D2, D3, Z0, Z1, Z2, Z3) do {                         \
    float4 gc_, gd_;                                                           \
    GCOL4((J2), gc_); GCOL4((J2) + 1, gd_);                                    \
    DM4(D0, 0.25f, ga,  0.75f, gb,  Z0);                                       \
    DM4(D1, 0.75f, gb,  0.25f, gc_, Z1);                                       \
    DM4(D2, 0.25f, gb,  0.75f, gc_, Z2);                                       \
    DM4(D3, 0.75f, gc_, 0.25f, gd_, Z3);                                       \
    ga = gc_; gb = gd_;                                                        \
} while (0)

// one output row: vblur (regs) -> ONE ds_write_b128 + TWO ds_read_b128
// neighbor exchange (wave-private, in-order DS) -> hblur -> log1p -> 16B store
#define OUT1(K, GY) do {                                                       \
    float4 v_;                                                                 \
    v_.x = H9(win[K].x, win[K+1].x, win[K+2].x, win[K+3].x, win[K+4].x,        \
              win[K+5].x, win[K+6].x, win[K+7].x, win[K+8].x);                 \
    v_.y = H9(win[K].y, win[K+1].y, win[K+2].y, win[K+3].y, win[K+4].y,        \
              win[K+5].y, win[K+6].y, win[K+7].y, win[K+8].y);                 \
    v_.z = H9(win[K].z, win[K+1].z, win[K+2].z, win[K+3].z, win[K+4].z,        \
              win[K+5].z, win[K+6].z, win[K+7].z, win[K+8].z);                 \
    v_.w = H9(win[K].w, win[K+1].w, win[K+2].w, win[K+3].w, win[K+4].w,        \
              win[K+5].w, win[K+6].w, win[K+7].w, win[K+8].w);                 \
    float* sl_ = ((K) & 1) ? EX1 : EX0;                                        \
    *reinterpret_cast<float4*>(sl_ + 4 * lane) = v_;                           \
    const float4 wl_ = *reinterpret_cast<const float4*>(sl_ + 4 * lnL);        \
    const float4 wr_ = *reinterpret_cast<const float4*>(sl_ + 4 * lnR);        \
    float4 rr_;                                                                \
    rr_.x = H9(wl_.x, wl_.y, wl_.z, wl_.w, v_.x, v_.y, v_.z, v_.w, wr_.x);     \
    rr_.y = H9(wl_.y, wl_.z, wl_.w, v_.x, v_.y, v_.z, v_.w, wr_.x, wr_.y);     \
    rr_.z = H9(wl_.z, wl_.w, v_.x, v_.y, v_.z, v_.w, wr_.x, wr_.y, wr_.z);     \
    rr_.w = H9(wl_.w, v_.x, v_.y, v_.z, v_.w, wr_.x, wr_.y, wr_.z, wr_.w);     \
    rr_.x = __logf(1.0f + fmaxf(rr_.x, 0.0f));                                 \
    rr_.y = __logf(1.0f + fmaxf(rr_.y, 0.0f));                                 \
    rr_.z = __logf(1.0f + fmaxf(rr_.z, 0.0f));                                 \
    rr_.w = __logf(1.0f + fmaxf(rr_.w, 0.0f));                                 \
    if (okst) *reinterpret_cast<float4*>(out + (size_t)(GY) * N + gxs) = rr_;  \
} while (0)

#define SLIDE4() do {                                                          \
    _Pragma("unroll")                                                          \
    for (int i_ = 0; i_ < 8; ++i_) win[i_] = win[i_ + 4];                      \
} while (0)

__global__ __launch_bounds__(256, 5)
void TensorAugment_79216376807666_kernel(const float* __restrict__ img,
                                         const float* __restrict__ noise,
                                         float* __restrict__ out) {
    __shared__ __align__(16) float SH[IPSZ + 4 * 512];       // 28.8 KB

    const int tid  = threadIdx.x;
    const int lane = tid & 63;
    const int wave = tid >> 6;

    float* const IP  = SH;
    float* const EX0 = SH + IPSZ + wave * 512;
    float* const EX1 = EX0 + 256;

    const int bid = blockIdx.x;
    const int sx  = bid % NSX;
    const int sy  = bid / NSX;
    const int x0  = sx * TXN;                        // staged cols x0-4 .. x0+255
    const int y0  = sy * 64;                         // block rows y0 .. y0+63

    // ---- block-uniform staged img ranges (x -> img rows, y -> img cols) ----
    int gxa = x0 - 4, gxb = x0 + BSPAN - 5;
    int mxa = symi(gxa), mxb = symi(gxb);
    int gxmin = min(mxa, mxb), gxmax = max(mxa, mxb);
    if (gxa <= 0) gxmin = 0;
    if (gxb >= N - 1) gxmax = N - 1;
    int umin = (N - 1) - gxmax, umax = (N - 1) - gxmin;
    int r0min = (umin - 1) >> 1;
    int r0max = (umax - 1) >> 1;
    int nrows = r0max - r0min + 2;                   // <= 132

    int gya = y0 - 4, gyb = y0 + 67;                 // block D rows y0-4..y0+67
    int mya = symi(gya), myb = symi(gyb);
    int gymin = min(mya, myb), gymax = max(mya, myb);
    if (gya <= 0) gymin = 0;
    if (gyb >= N - 1) gymax = N - 1;
    int c0min = (gymin - 1) >> 1;

    int ncols = ((gymax - 1) >> 1) - c0min + 2;      // <= 38

    // ---- cooperative patch staging (R5 pattern): lane = col, coalesced ----
    {
        const int c = lane;
        if (c < ncols) {
            const int ic = min(max(c0min + c, 0), NIMG - 1);
            for (int r = wave; r < nrows; r += 4) {
                const int ir = min(max(r0min + r, 0), NIMG - 1);
                IP[r * PPI + c] = img[(size_t)ir * NIMG + ic];
            }
        }
    }

    // ---- per-wave / per-lane setup (overlaps staging loads) ----
    const int y0w = y0 + HRW * wave;
    const int gxs = x0 - 4 + 4 * lane;               // lane's first col (16B aligned)
    const bool okst = (lane >= 1) && (lane <= 62) && (gxs >= 0) && (gxs <= N - 4);
    const bool xin  = (sx > 0) && (sx < NSX - 1);
    const bool yin  = (y0w >= 4) && (y0w + 19 <= N - 1);
    const bool fast = xin && yin;
    const int lnL = (lane == 0) ? 0 : lane - 1;
    const int lnR = (lane == 63) ? 63 : lane + 1;

    const int a    = gxs >> 1;                       // fast path: gxs = 2a
    const int ipb  = (2047 - a - r0min) * PPI;
    const float* const ipg = IP + ipb;
    const int jb   = ((y0w - 5) >> 1) - c0min;       // wave's g-col base
    const float* const nzb = noise + ((size_t)(y0w - 4) * N + gxs);
#define LDNZ(DR) (*reinterpret_cast<const float4*>(nzb + (size_t)(DR) * N))

    // ---- issue-early prologue noise (1KB segments; hides under staging) ----
    float4 np0, np1, np2, np3, np4, np5, np6, np7, np8, np9, npa, npb;
    if (fast) {
        np0 = LDNZ(0);  np1 = LDNZ(1);  np2 = LDNZ(2);  np3 = LDNZ(3);
        np4 = LDNZ(4);  np5 = LDNZ(5);  np6 = LDNZ(6);  np7 = LDNZ(7);
        np8 = LDNZ(8);  np9 = LDNZ(9);  npa = LDNZ(10); npb = LDNZ(11);
    }

    __syncthreads();                                 // the only barrier

    float4 win[12];

    if (fast) {
        // ================= fast path =================
        float4 ga, gb;
        GCOL4(jb, ga);
        GCOL4(jb + 1, gb);

        // prologue: D rows 0..11 from pre-issued noise
        PROD4(jb + 2, win[0], win[1], win[2],  win[3],  np0, np1, np2, np3);
        PROD4(jb + 4, win[4], win[5], win[6],  win[7],  np4, np5, np6, np7);
        PROD4(jb + 6, win[8], win[9], win[10], win[11], np8, np9, npa, npb);

        // chunk 0: out rows y0w..+3, produce D 12..15
        {
            float4 n0 = LDNZ(12), n1 = LDNZ(13), n2 = LDNZ(14), n3 = LDNZ(15);
            OUT1(0, y0w + 0); OUT1(1, y0w + 1); OUT1(2, y0w + 2); OUT1(3, y0w + 3);
            SLIDE4();
            PROD4(jb + 8, win[8], win[9], win[10], win[11], n0, n1, n2, n3);
        }
        // chunk 1: out rows +4..7, produce D 16..19
        {
            float4 n0 = LDNZ(16), n1 = LDNZ(17), n2 = LDNZ(18), n3 = LDNZ(19);
            OUT1(0, y0w + 4); OUT1(1, y0w + 5); OUT1(2, y0w + 6); OUT1(3, y0w + 7);
            SLIDE4();
            PROD4(jb + 10, win[8], win[9], win[10], win[11], n0, n1, n2, n3);
        }
        // chunk 2: out rows +8..11, produce D 20..23
        {
            float4 n0 = LDNZ(20), n1 = LDNZ(21), n2 = LDNZ(22), n3 = LDNZ(23);
            OUT1(0, y0w + 8); OUT1(1, y0w + 9); OUT1(2, y0w + 10); OUT1(3, y0w + 11);
            SLIDE4();
            PROD4(jb + 12, win[8], win[9], win[10], win[11], n0, n1, n2, n3);
        }
        // chunk 3: out rows +12..15
        OUT1(0, y0w + 12); OUT1(1, y0w + 13); OUT1(2, y0w + 14); OUT1(3, y0w + 15);
    } else {
        // ================= generic edge path (R4-verified 4-col form) ======
        const int gxm0 = symi(gxs + 0), gxm1 = symi(gxs + 1);
        const int gxm2 = symi(gxs + 2), gxm3 = symi(gxs + 3);
        const int u0 = (N - 1) - gxm0, u1 = (N - 1) - gxm1;
        const int u2 = (N - 1) - gxm2, u3 = (N - 1) - gxm3;
        const int A0 = (((u0 - 1) >> 1) - r0min) * PPI;
        const int A1 = (((u1 - 1) >> 1) - r0min) * PPI;
        const int A2 = (((u2 - 1) >> 1) - r0min) * PPI;
        const int A3 = (((u3 - 1) >> 1) - r0min) * PPI;
        const float w10 = (u0 & 1) ? 0.25f : 0.75f, w00 = 1.0f - w10;
        const float w11 = (u1 & 1) ? 0.25f : 0.75f, w01 = 1.0f - w11;
        const float w12 = (u2 & 1) ? 0.25f : 0.75f, w02 = 1.0f - w12;
        const float w13 = (u3 & 1) ? 0.25f : 0.75f, w03 = 1.0f - w13;

        auto nzg = [&](int dr) -> float4 {
            const float* nr = noise + (size_t)symi(y0w - 4 + dr) * N;
            float4 r;
            r.x = nr[gxm0]; r.y = nr[gxm1]; r.z = nr[gxm2]; r.w = nr[gxm3];
            return r;
        };
        auto dgen = [&](int dr, float4 nz) -> float4 {
            const int gym = symi(y0w - 4 + dr);
            const int jc  = ((gym - 1) >> 1) - c0min;
            const float wc1 = (gym & 1) ? 0.25f : 0.75f;
            const float wc0 = 1.0f - wc1;
            float4 r;
            {
                const float t = fmaf(wc0, IP[A0 + jc], wc1 * IP[A0 + jc + 1]);
                const float b = fmaf(wc0, IP[A0 + PPI + jc], wc1 * IP[A0 + PPI + jc + 1]);
                r.x = fmaf(w00, t, fmaf(w10, b, 0.01f * nz.x));
            }
            {
                const float t = fmaf(wc0, IP[A1 + jc], wc1 * IP[A1 + jc + 1]);
                const float b = fmaf(wc0, IP[A1 + PPI + jc], wc1 * IP[A1 + PPI + jc + 1]);
                r.y = fmaf(w01, t, fmaf(w11, b, 0.01f * nz.y));
            }
            {
                const float t = fmaf(wc0, IP[A2 + jc], wc1 * IP[A2 + jc + 1]);
                const float b = fmaf(wc0, IP[A2 + PPI + jc], wc1 * IP[A2 + PPI + jc + 1]);
                r.z = fmaf(w02, t, fmaf(w12, b, 0.01f * nz.z));
            }
            {
                const float t = fmaf(wc0, IP[A3 + jc], wc1 * IP[A3 + jc + 1]);
                const float b = fmaf(wc0, IP[A3 + PPI + jc], wc1 * IP[A3 + PPI + jc + 1]);
                r.w = fmaf(w03, t, fmaf(w13, b, 0.01f * nz.w));
            }
            return r;
        };

#pragma unroll
        for (int j = 0; j < 12; ++j) win[j] = dgen(j, nzg(j));

#pragma unroll
        for (int c = 0; c < 4; ++c) {
            float4 n0, n1, n2, n3;
            if (c < 3) { n0 = nzg(12 + 4 * c); n1 = nzg(13 + 4 * c);
                         n2 = nzg(14 + 4 * c); n3 = nzg(15 + 4 * c); }
            OUT1(0, y0w + 4 * c + 0); OUT1(1, y0w + 4 * c + 1);
            OUT1(2, y0w + 4 * c + 2); OUT1(3, y0w + 4 * c + 3);
            if (c < 3) {
                SLIDE4();
                win[8]  = dgen(12 + 4 * c, n0);
                win[9]  = dgen(13 + 4 * c, n1);
                win[10] = dgen(14 + 4 * c, n2);
                win[11] = dgen(15 + 4 * c, n3);
            }
        }
    }
#undef LDNZ
}

extern "C" void kernel_launch(void* const* d_in, const int* in_sizes, int n_in,
                              void* d_out, int out_size, void* d_ws, size_t ws_size,
                              hipStream_t stream) {
    const float* img   = (const float*)d_in[0];   // (1, 2048, 2048) f32
    const float* noise = (const float*)d_in[1];   // (1, 4096, 4096) f32
    float* out = (float*)d_out;                   // (1, 4096, 4096) f32

    dim3 grid(NBLK);                              // 1088 blocks x 256
    TensorAugment_79216376807666_kernel<<<grid, 256, 0, stream>>>(img, noise, out);
}

// Round 9
// 138.116 us; speedup vs baseline: 1.3673x; 1.3673x over previous
//
#include <hip/hip_runtime.h>
#include <math.h>

#define N      4096
#define NIMG   2048
#define SPAN   128           // staged x-cols per block (64 lanes x float2)
#define TXN    120           // net output cols per block
#define HRW    16            // output rows per wave (block = 64 rows)
#define PP     66            // img patch pitch (banks stride 2 -> 2-way, free)
#define PR     66            // img patch rows (span/2 + 2)
#define NSX    35            // ceil(4096/120)
#define NSY    64            // 4096/64
#define NBLK   (NSX * NSY)   // 2240 blocks = 8 XCDs x 280

// Gaussian kernel sigma=1, r=4 (double-precision eval of reference formula)
#define KW0 0.00013383063f
#define KW1 0.00443186160f
#define KW2 0.05399112800f
#define KW3 0.24197144000f
#define KW4 0.39894346870f

__device__ __forceinline__ int symi(int g) {
    g = (g < 0) ? (-1 - g) : g;
    g = (g >= N) ? (2 * N - 1 - g) : g;
    return g;
}

#define H9(A,B,C,D,E,F,G,H,I)                                                  \
    fmaf(KW0,(A), fmaf(KW1,(B), fmaf(KW2,(C), fmaf(KW3,(D), fmaf(KW4,(E),      \
    fmaf(KW3,(F), fmaf(KW2,(G), fmaf(KW1,(H), KW0*(I)))))))))

// g-column J (abs staged col): bilinear-x for this lane's 2 output cols.
#define GCOL2(J, G) do {                                                       \
    const float p0_ = ipg[(J) - PP];                                           \
    const float p1_ = ipg[(J)];                                                \
    const float p2_ = ipg[(J) + PP];                                           \
    (G).x = fmaf(0.75f, p1_, 0.25f * p2_);                                     \
    (G).y = fmaf(0.25f, p0_, 0.75f * p1_);                                     \
} while (0)

// 4 D rows from carried g-cols (ga,gb) + 2 fresh (J2, J2+1); verified R3/R5
// interior weight pattern: (.25,.75)(.75,.25)(.25,.75)(.75,.25)
#define PROD4(J2, D0, D1, D2, D3, Z0, Z1, Z2, Z3) do {                         \
    float2 gc_, gd_;                                                           \
    GCOL2((J2), gc_); GCOL2((J2) + 1, gd_);                                    \
    (D0).x = fmaf(0.25f, ga.x, fmaf(0.75f, gb.x, 0.01f * (Z0).x));             \
    (D0).y = fmaf(0.25f, ga.y, fmaf(0.75f, gb.y, 0.01f * (Z0).y));             \
    (D1).x = fmaf(0.75f, gb.x, fmaf(0.25f, gc_.x, 0.01f * (Z1).x));            \
    (D1).y = fmaf(0.75f, gb.y, fmaf(0.25f, gc_.y, 0.01f * (Z1).y));            \
    (D2).x = fmaf(0.25f, gb.x, fmaf(0.75f, gc_.x, 0.01f * (Z2).x));            \
    (D2).y = fmaf(0.25f, gb.y, fmaf(0.75f, gc_.y, 0.01f * (Z2).y));            \
    (D3).x = fmaf(0.75f, gc_.x, fmaf(0.25f, gd_.x, 0.01f * (Z3).x));           \
    (D3).y = fmaf(0.75f, gc_.y, fmaf(0.25f, gd_.y, 0.01f * (Z3).y));           \
    ga = gc_; gb = gd_;                                                        \
} while (0)

// one output row: vblur (registers) -> float2 LDS exchange (wave-private,
// in-order DS, alternating slots) -> hblur -> relu/log1p -> float2 store
#define OUT1(K, GY) do {                                                       \
    float2 v_;                                                                 \
    v_.x = H9(win[K].x, win[K+1].x, win[K+2].x, win[K+3].x, win[K+4].x,        \
              win[K+5].x, win[K+6].x, win[K+7].x, win[K+8].x);                 \
    v_.y = H9(win[K].y, win[K+1].y, win[K+2].y, win[K+3].y, win[K+4].y,        \
              win[K+5].y, win[K+6].y, win[K+7].y, win[K+8].y);                 \
    float* sl_ = ((K) & 1) ? EX1 : EX0;                                        \
    *reinterpret_cast<float2*>(sl_ + 2 * lane) = v_;                           \
    const float2 l0_ = *reinterpret_cast<const float2*>(sl_ + oL0);            \
    const float2 l1_ = *reinterpret_cast<const float2*>(sl_ + oL1);            \
    const float2 r0_ = *reinterpret_cast<const float2*>(sl_ + oR0);            \
    const float2 r1_ = *reinterpret_cast<const float2*>(sl_ + oR1);            \
    float ox_ = KW0 * l0_.x; ox_ = fmaf(KW1, l0_.y, ox_);                      \
    ox_ = fmaf(KW2, l1_.x, ox_); ox_ = fmaf(KW3, l1_.y, ox_);                  \
    ox_ = fmaf(KW4, v_.x, ox_);  ox_ = fmaf(KW3, v_.y, ox_);                   \
    ox_ = fmaf(KW2, r0_.x, ox_); ox_ = fmaf(KW1, r0_.y, ox_);                  \
    ox_ = fmaf(KW0, r1_.x, ox_);                                               \
    float oy_ = KW0 * l0_.y; oy_ = fmaf(KW1, l1_.x, oy_);                      \
    oy_ = fmaf(KW2, l1_.y, oy_); oy_ = fmaf(KW3, v_.x, oy_);                   \
    oy_ = fmaf(KW4, v_.y, oy_);  oy_ = fmaf(KW3, r0_.x, oy_);                  \
    oy_ = fmaf(KW2, r0_.y, oy_); oy_ = fmaf(KW1, r1_.x, oy_);                  \
    oy_ = fmaf(KW0, r1_.y, oy_);                                               \
    float2 rr_;                                                                \
    rr_.x = __logf(1.0f + fmaxf(ox_, 0.0f));                                   \
    rr_.y = __logf(1.0f + fmaxf(oy_, 0.0f));                                   \
    if (okst) *reinterpret_cast<float2*>(out + (size_t)(GY) * N + gxs) = rr_;  \
} while (0)

#define SLIDE4() do {                                                          \
    _Pragma("unroll")                                                          \
    for (int i_ = 0; i_ < 8; ++i_) win[i_] = win[i_ + 4];                      \
} while (0)

__global__ __launch_bounds__(256, 5)
void TensorAugment_79216376807666_kernel(const float* __restrict__ img,
                                         const float* __restrict__ noise,
                                         float* __restrict__ out) {
    __shared__ __align__(16) float SH[PR * PP + 4 * 256];    // 21.5 KB

    const int tid  = threadIdx.x;
    const int lane = tid & 63;
    const int wave = tid >> 6;

    float* const IP  = SH;
    float* const EX0 = SH + PR * PP + wave * 256;
    float* const EX1 = EX0 + 128;

    // ---- XCD y-band swizzle: xcd owns a contiguous 8-row band (bijective:
    //      2240 = 8 * 280, band = 280/NSX = 8 block-rows) ----
    const int bid0 = blockIdx.x;
    const int xcd  = bid0 & 7;
    const int ii   = bid0 >> 3;                      // 0..279
    const int sx   = ii % NSX;
    const int sy   = xcd * (NSY / 8) + ii / NSX;
    const int x0   = sx * TXN;                       // staged cols x0-4 .. x0+123
    const int y0   = sy * 64;                        // block output rows y0..y0+63

    // ---- block-uniform staged img ranges (x -> img rows, y -> img cols) ----
    int gxa = x0 - 4, gxb = x0 + SPAN - 5;
    int mxa = symi(gxa), mxb = symi(gxb);
    int gxmin = min(mxa, mxb), gxmax = max(mxa, mxb);
    if (gxa <= 0) gxmin = 0;
    if (gxb >= N - 1) gxmax = N - 1;
    int umin = (N - 1) - gxmax, umax = (N - 1) - gxmin;
    int r0min = (umin - 1) >> 1;
    int r0max = (umax - 1) >> 1;
    int nrows = r0max - r0min + 2;                   // <= 66

    int gya = y0 - 4, gyb = y0 + 67;                 // block D rows y0-4 .. y0+67
    int mya = symi(gya), myb = symi(gyb);
    int gymin = min(mya, myb), gymax = max(mya, myb);
    if (gya <= 0) gymin = 0;
    if (gyb >= N - 1) gymax = N - 1;
    int c0min = (gymin - 1) >> 1;

    // ---- cooperative patch staging, two-phase: 17 loads ALL in flight,
    //      then 17 ds_writes (row clamped -> fixed trip count, no serial
    //      load->write round trips) ----
    {
        const int gcol = min(max(c0min + lane, 0), NIMG - 1);
        float sv[17];
#pragma unroll
        for (int k = 0; k < 17; ++k) {
            const int r  = min(wave + 4 * k, nrows - 1);
            const int ir = min(max(r0min + r, 0), NIMG - 1);
            sv[k] = img[(size_t)ir * NIMG + gcol];
        }
#pragma unroll
        for (int k = 0; k < 17; ++k) {
            const int r = min(wave + 4 * k, nrows - 1);
            IP[r * PP + lane] = sv[k];               // dup rows rewrite same value
        }
    }

    // ---- per-wave / per-lane setup ----
    const int y0w = y0 + HRW * wave;
    const int gxs = x0 - 4 + 2 * lane;               // lane's first output col
    const bool okst = (lane >= 2) && (lane <= 61) && (gxs <= N - 2);
    const bool yin  = (y0w >= 4) && (y0w + 19 <= N - 1);
    const bool xin  = (sx > 0) && (sx < NSX - 1);
    const bool fast = xin && yin;
    const int oL0 = max(2 * lane - 4, 0), oL1 = max(2 * lane - 2, 0);
    const int oR0 = min(2 * lane + 2, 126), oR1 = min(2 * lane + 4, 126);

    const int a    = (x0 >> 1) - 2 + lane;           // gxs = 2a (fast path)
    const int ipb  = (2047 - a - r0min) * PP;
    const float* const ipg = IP + ipb;
    const int jb   = ((y0w - 5) >> 1) - c0min;       // wave's g-col base
    const float* const nzb = noise + ((size_t)(y0w - 4) * N + gxs);
#define LDNZ(DR) (*reinterpret_cast<const float2*>(nzb + (size_t)(DR) * N))

    // ---- pre-barrier noise: prologue rows 0..11 + chunk-0 rows 12..15 ----
    float2 npre[12];
    float2 nA0, nA1, nA2, nA3;
    if (fast) {
#pragma unroll
        for (int j = 0; j < 12; ++j) npre[j] = LDNZ(j);
        nA0 = LDNZ(12); nA1 = LDNZ(13); nA2 = LDNZ(14); nA3 = LDNZ(15);
    }

    __syncthreads();                                 // the only barrier

    float2 win[12];

    if (fast) {
        // ================= fast path =================
        // issue chunk-1 noise immediately (2-chunk-deep prefetch)
        float2 nB0 = LDNZ(16), nB1 = LDNZ(17), nB2 = LDNZ(18), nB3 = LDNZ(19);

        float2 ga, gb;
        GCOL2(jb, ga);
        GCOL2(jb + 1, gb);

        // prologue: D rows 0..11 from pre-barrier noise
        PROD4(jb + 2, win[0], win[1], win[2],  win[3],  npre[0], npre[1], npre[2],  npre[3]);
        PROD4(jb + 4, win[4], win[5], win[6],  win[7],  npre[4], npre[5], npre[6],  npre[7]);
        PROD4(jb + 6, win[8], win[9], win[10], win[11], npre[8], npre[9], npre[10], npre[11]);

        // chunk 0: issue chunk-2 noise, compute rows 0..3, append D 12..15
        float2 nC0 = LDNZ(20), nC1 = LDNZ(21), nC2 = LDNZ(22), nC3 = LDNZ(23);
        OUT1(0, y0w + 0); OUT1(1, y0w + 1); OUT1(2, y0w + 2); OUT1(3, y0w + 3);
        SLIDE4();
        PROD4(jb + 8, win[8], win[9], win[10], win[11], nA0, nA1, nA2, nA3);

        // chunk 1: rows 4..7, append D 16..19 (nB loaded ~3 chunks ago)
        OUT1(0, y0w + 4); OUT1(1, y0w + 5); OUT1(2, y0w + 6); OUT1(3, y0w + 7);
        SLIDE4();
        PROD4(jb + 10, win[8], win[9], win[10], win[11], nB0, nB1, nB2, nB3);

        // chunk 2: rows 8..11, append D 20..23 (nC loaded 2 chunks ago)
        OUT1(0, y0w + 8); OUT1(1, y0w + 9); OUT1(2, y0w + 10); OUT1(3, y0w + 11);
        SLIDE4();
        PROD4(jb + 12, win[8], win[9], win[10], win[11], nC0, nC1, nC2, nC3);

        // chunk 3: rows 12..15
        OUT1(0, y0w + 12); OUT1(1, y0w + 13); OUT1(2, y0w + 14); OUT1(3, y0w + 15);
    } else {
        // ================= generic edge path =================
        const int gxm0 = symi(gxs), gxm1 = symi(gxs + 1);
        const int u0 = (N - 1) - gxm0, u1 = (N - 1) - gxm1;
        const int A0 = (((u0 - 1) >> 1) - r0min) * PP;
        const int A1 = (((u1 - 1) >> 1) - r0min) * PP;
        const float w10 = (u0 & 1) ? 0.25f : 0.75f, w00 = 1.0f - w10;
        const float w11 = (u1 & 1) ? 0.25f : 0.75f, w01 = 1.0f - w11;

        auto nzg = [&](int dr) -> float2 {
            const float* nr = noise + (size_t)symi(y0w - 4 + dr) * N;
            float2 r; r.x = nr[gxm0]; r.y = nr[gxm1]; return r;
        };
        auto dgen = [&](int dr, float2 nz) -> float2 {
            const int gym = symi(y0w - 4 + dr);
            const int jc  = ((gym - 1) >> 1) - c0min;
            const float wc1 = (gym & 1) ? 0.25f : 0.75f;
            const float wc0 = 1.0f - wc1;
            float2 r;
            {
                const float t = fmaf(wc0, IP[A0 + jc], wc1 * IP[A0 + jc + 1]);
                const float b = fmaf(wc0, IP[A0 + PP + jc], wc1 * IP[A0 + PP + jc + 1]);
                r.x = fmaf(w00, t, fmaf(w10, b, 0.01f * nz.x));
            }
            {
                const float t = fmaf(wc0, IP[A1 + jc], wc1 * IP[A1 + jc + 1]);
                const float b = fmaf(wc0, IP[A1 + PP + jc], wc1 * IP[A1 + PP + jc + 1]);
                r.y = fmaf(w01, t, fmaf(w11, b, 0.01f * nz.y));
            }
            return r;
        };

#pragma unroll
        for (int j = 0; j < 12; ++j) win[j] = dgen(j, nzg(j));

#pragma unroll
        for (int c = 0; c < 4; ++c) {
            float2 n0, n1, n2, n3;
            if (c < 3) { n0 = nzg(12 + 4 * c); n1 = nzg(13 + 4 * c);
                         n2 = nzg(14 + 4 * c); n3 = nzg(15 + 4 * c); }
            OUT1(0, y0w + 4 * c + 0); OUT1(1, y0w + 4 * c + 1);
            OUT1(2, y0w + 4 * c + 2); OUT1(3, y0w + 4 * c + 3);
            if (c < 3) {
                SLIDE4();
                win[8]  = dgen(12 + 4 * c, n0);
                win[9]  = dgen(13 + 4 * c, n1);
                win[10] = dgen(14 + 4 * c, n2);
                win[11] = dgen(15 + 4 * c, n3);
            }
        }
    }
#undef LDNZ
}

extern "C" void kernel_launch(void* const* d_in, const int* in_sizes, int n_in,
                              void* d_out, int out_size, void* d_ws, size_t ws_size,
                              hipStream_t stream) {
    const float* img   = (const float*)d_in[0];   // (1, 2048, 2048) f32
    const float* noise = (const float*)d_in[1];   // (1, 4096, 4096) f32
    float* out = (float*)d_out;                   // (1, 4096, 4096) f32

    dim3 grid(NBLK);                              // 2240 blocks x 256
    TensorAugment_79216376807666_kernel<<<grid, 256, 0, stream>>>(img, noise, out);
}